// Round 2
// baseline (6291.933 us; speedup 1.0000x reference)
//
#include <hip/hip_runtime.h>

#define BATCH   4
#define NPTS    8192
#define NPOINT  2048
#define NSAMPLE 32
#define NCH     67
#define NOUT    128
#define NP      4      // centers per conv block
#define FPS_T   1024
#define KPT     (NPTS / FPS_T)   // 8 points per thread
#define NWAVE   (FPS_T / 64)     // 16 waves

// ---------------------------------------------------------------------------
// FPS: one block per batch. 1024 threads x 8 points in registers.
// Bit-exact vs reference: per-op rounding (contract off), sum order
// ((dx^2+dy^2)+dz^2), argmax = first occurrence (smallest index wins ties).
// Single __syncthreads per iteration: candidate coords ride the shuffle
// reduction; wave partials double-buffered by iteration parity; all threads
// redundantly reduce the 16 wave partials (broadcast LDS reads).
// ---------------------------------------------------------------------------
__global__ __launch_bounds__(FPS_T) void fps_kernel(
    const float* __restrict__ points, float* __restrict__ new_xyz)
{
#pragma clang fp contract(off)
    const int b = blockIdx.x;
    const int t = threadIdx.x;
    const float* pts = points + (size_t)b * NPTS * 3;

    float x[KPT], y[KPT], z[KPT], dist[KPT];
#pragma unroll
    for (int k = 0; k < KPT; ++k) {
        int i = t + (k << 10);
        x[k] = pts[3 * i + 0];
        y[k] = pts[3 * i + 1];
        z[k] = pts[3 * i + 2];
        dist[k] = 10000000000.0f;
    }

    __shared__ float pv[2][NWAVE];
    __shared__ int   pi[2][NWAVE];
    __shared__ float px[2][NWAVE], py[2][NWAVE], pz[2][NWAVE];

    // first center = point 0; all threads broadcast-read it from global
    float cx = pts[0], cy = pts[1], cz = pts[2];
    if (t == 0) {
        float* o = new_xyz + (size_t)b * NPOINT * 3;
        o[0] = cx; o[1] = cy; o[2] = cz;
    }

    const int lane = t & 63;
    const int w    = t >> 6;

    for (int it = 1; it < NPOINT; ++it) {
        float bv = -1.0f; int bi = 0;
        float bx = 0.f, by = 0.f, bz = 0.f;
#pragma unroll
        for (int k = 0; k < KPT; ++k) {
            float dx = x[k] - cx;
            float dy = y[k] - cy;
            float dz = z[k] - cz;
            float d  = ((dx * dx) + (dy * dy)) + (dz * dz);
            float dk = fminf(dist[k], d);
            dist[k] = dk;
            // k ascending => strict > keeps the smallest index on ties
            if (dk > bv) { bv = dk; bi = t + (k << 10); bx = x[k]; by = y[k]; bz = z[k]; }
        }
        // wave argmax reduce, carrying idx + coords; lane 0 gets wave best
#pragma unroll
        for (int off = 32; off >= 1; off >>= 1) {
            float ov = __shfl_down(bv, off);
            int   oi = __shfl_down(bi, off);
            float ox = __shfl_down(bx, off);
            float oy = __shfl_down(by, off);
            float oz = __shfl_down(bz, off);
            if (ov > bv || (ov == bv && oi < bi)) {
                bv = ov; bi = oi; bx = ox; by = oy; bz = oz;
            }
        }
        const int par = it & 1;
        if (lane == 0) {
            pv[par][w] = bv; pi[par][w] = bi;
            px[par][w] = bx; py[par][w] = by; pz[par][w] = bz;
        }
        __syncthreads();
        // all threads redundantly reduce the 16 wave partials (broadcast reads)
        float fv = pv[par][0]; int fi = pi[par][0]; int fw = 0;
#pragma unroll
        for (int q = 1; q < NWAVE; ++q) {
            float v = pv[par][q]; int i2 = pi[par][q];
            if (v > fv || (v == fv && i2 < fi)) { fv = v; fi = i2; fw = q; }
        }
        cx = px[par][fw]; cy = py[par][fw]; cz = pz[par][fw];
        if (t == 0) {
            float* o = new_xyz + ((size_t)b * NPOINT + it) * 3;
            o[0] = cx; o[1] = cy; o[2] = cz;
        }
    }
}

// ---------------------------------------------------------------------------
// Ball query: one wave per center. Ascending scan collects the first (i.e.
// smallest-index) NSAMPLE points with d2 < r2, padded with the first hit.
// ---------------------------------------------------------------------------
__global__ __launch_bounds__(256) void ballq_kernel(
    const float* __restrict__ points, const float* __restrict__ new_xyz,
    int* __restrict__ ballidx)
{
#pragma clang fp contract(off)
    const int wid  = (int)((blockIdx.x * 256 + threadIdx.x) >> 6);
    const int lane = threadIdx.x & 63;
    const int b = wid / NPOINT;
    const float* ctr = new_xyz + (size_t)wid * 3;
    const float cx = ctr[0], cy = ctr[1], cz = ctr[2];
    const float* pts = points + (size_t)b * NPTS * 3;
    int* out = ballidx + (size_t)wid * NSAMPLE;
    // NumPy/JAX promote the python double 0.04 to f32 — NOT 0.2f*0.2f.
    const float r2 = (float)(0.2 * 0.2);

    int cnt = 0;
    int first = 0;
    bool havefirst = false;
    for (int base = 0; base < NPTS && cnt < NSAMPLE; base += 64) {
        const int j = base + lane;
        float dx = pts[3 * j + 0] - cx;
        float dy = pts[3 * j + 1] - cy;
        float dz = pts[3 * j + 2] - cz;
        float d2 = ((dx * dx) + (dy * dy)) + (dz * dz);
        const bool in = d2 < r2;
        unsigned long long m = __ballot(in);
        if (in) {
            int pos = cnt + __popcll(m & ((1ull << lane) - 1ull));
            if (pos < NSAMPLE) out[pos] = j;
        }
        if (!havefirst && m != 0ull) {
            first = base + (__ffsll((long long)m) - 1);
            havefirst = true;
        }
        cnt += __popcll(m);
    }
    if (lane >= cnt && lane < NSAMPLE) out[lane] = first;  // pad with first
}

// ---------------------------------------------------------------------------
// Gather + conv: block = NP centers, 128 threads = 128 output channels.
// g[p][c][s] staged in LDS; fp32 FMA accumulate (tolerance is loose here).
// ---------------------------------------------------------------------------
__global__ __launch_bounds__(128) void conv_kernel(
    const float* __restrict__ points, const float* __restrict__ features,
    const float* __restrict__ weight, const float* __restrict__ new_xyz,
    const int* __restrict__ ballidx, float* __restrict__ conv_out)
{
    __shared__ float g[NP][NCH][NSAMPLE];
    const int t = threadIdx.x;
    const int bp0 = blockIdx.x * NP;                // global center index base
    const int b = bp0 / NPOINT;
    const float* pts = points + (size_t)b * NPTS * 3;
    const float* fts = features + (size_t)b * NPTS * 64;

    // gather: 128 slots == 128 threads; slot = p*32+s
    {
        const int p = t >> 5;
        const int s = t & 31;
        const int ci = bp0 + p;
        const int j = ballidx[(size_t)ci * NSAMPLE + s];
        const float* ctr = new_xyz + (size_t)ci * 3;
        const float* pj = pts + 3 * j;
        g[p][0][s] = pj[0] - ctr[0];
        g[p][1][s] = pj[1] - ctr[1];
        g[p][2][s] = pj[2] - ctr[2];
        const float4* fj = (const float4*)(fts + (size_t)j * 64);
#pragma unroll
        for (int c4 = 0; c4 < 16; ++c4) {
            float4 v = fj[c4];
            g[p][3 + 4 * c4 + 0][s] = v.x;
            g[p][3 + 4 * c4 + 1][s] = v.y;
            g[p][3 + 4 * c4 + 2][s] = v.z;
            g[p][3 + 4 * c4 + 3][s] = v.w;
        }
    }
    __syncthreads();

    const int o = t;
    float acc0 = 0.f, acc1 = 0.f, acc2 = 0.f, acc3 = 0.f;
    const float* wr = weight + (size_t)o * NCH * NSAMPLE;
    for (int c = 0; c < NCH; ++c) {
        const float4* w4 = (const float4*)(wr + c * NSAMPLE);
#pragma unroll
        for (int s4 = 0; s4 < 8; ++s4) {
            float4 wv = w4[s4];
            float4 g0 = *(const float4*)&g[0][c][s4 * 4];
            float4 g1 = *(const float4*)&g[1][c][s4 * 4];
            float4 g2 = *(const float4*)&g[2][c][s4 * 4];
            float4 g3 = *(const float4*)&g[3][c][s4 * 4];
            acc0 += g0.x * wv.x + g0.y * wv.y + g0.z * wv.z + g0.w * wv.w;
            acc1 += g1.x * wv.x + g1.y * wv.y + g1.z * wv.z + g1.w * wv.w;
            acc2 += g2.x * wv.x + g2.y * wv.y + g2.z * wv.z + g2.w * wv.w;
            acc3 += g3.x * wv.x + g3.y * wv.y + g3.z * wv.z + g3.w * wv.w;
        }
    }
    float* outp = conv_out + (size_t)bp0 * NOUT;
    outp[0 * NOUT + o] = acc0;
    outp[1 * NOUT + o] = acc1;
    outp[2 * NOUT + o] = acc2;
    outp[3 * NOUT + o] = acc3;
}

extern "C" void kernel_launch(void* const* d_in, const int* in_sizes, int n_in,
                              void* d_out, int out_size, void* d_ws, size_t ws_size,
                              hipStream_t stream)
{
    const float* points   = (const float*)d_in[0];
    const float* features = (const float*)d_in[1];
    const float* weight   = (const float*)d_in[2];

    float* new_xyz = (float*)d_out;                              // (4,2048,3)
    float* conv    = (float*)d_out + (size_t)BATCH * NPOINT * 3; // (4,2048,128)

    int* ballidx = (int*)d_ws;                 // (4,2048,32)

    fps_kernel<<<BATCH, FPS_T, 0, stream>>>(points, new_xyz);
    ballq_kernel<<<(BATCH * NPOINT * 64) / 256, 256, 0, stream>>>(points, new_xyz, ballidx);
    conv_kernel<<<(BATCH * NPOINT) / NP, 128, 0, stream>>>(points, features, weight, new_xyz, ballidx, conv);
}

// Round 3
// 2541.180 us; speedup vs baseline: 2.4760x; 2.4760x over previous
//
#include <hip/hip_runtime.h>

#define BATCH   4
#define NPTS    8192
#define NPOINT  2048
#define NSAMPLE 32
#define NCH     67
#define NOUT    128
#define NP      4      // centers per conv block
#define FPS_T   256
#define KPT     (NPTS / FPS_T)   // 32 points per thread
#define NWAVE   (FPS_T / 64)     // 4 waves

// ---------------------------------------------------------------------------
// FPS: one block per batch, 256 threads (1 wave/SIMD), 32 points/thread in
// registers. Bit-exact vs reference: contract off, sum order
// ((dx^2+dy^2)+dz^2), argmax = first occurrence (smallest index on ties).
// Argmax carried as packed u64 key: hi = float bits of dist (dist>=0 so
// unsigned compare is monotone), lo = ~idx (so bigger key == smaller idx on
// equal dist). One barrier/iter; center coords fetched from a 96 KB LDS
// point cache by every thread (broadcast reads).
// ---------------------------------------------------------------------------
__global__ __launch_bounds__(FPS_T, 1) void fps_kernel(
    const float* __restrict__ points, float* __restrict__ new_xyz)
{
#pragma clang fp contract(off)
    const int b = blockIdx.x;
    const int t = threadIdx.x;
    const float* pts = points + (size_t)b * NPTS * 3;

    __shared__ float px[NPTS], py[NPTS], pz[NPTS];
    __shared__ unsigned long long pk[2][NWAVE];

    float x[KPT], y[KPT], z[KPT], dist[KPT];
#pragma unroll
    for (int k = 0; k < KPT; ++k) {
        const int i = (k << 8) + t;
        const float xx = pts[3 * i + 0];
        const float yy = pts[3 * i + 1];
        const float zz = pts[3 * i + 2];
        x[k] = xx; y[k] = yy; z[k] = zz;
        dist[k] = 10000000000.0f;
        px[i] = xx; py[i] = yy; pz[i] = zz;
    }

    float cx = pts[0], cy = pts[1], cz = pts[2];  // first center = point 0
    if (t == 0) {
        float* o = new_xyz + (size_t)b * NPOINT * 3;
        o[0] = cx; o[1] = cy; o[2] = cz;
    }
    const int lane = t & 63;
    const int w    = t >> 6;
    __syncthreads();

    for (int it = 1; it < NPOINT; ++it) {
        // ---- phase A: min-update + thread-local argmax (k index only) ----
        float bv; int bk = 0;
        {
            float dx = x[0] - cx, dy = y[0] - cy, dz = z[0] - cz;
            float d  = ((dx * dx) + (dy * dy)) + (dz * dz);
            float dk = fminf(dist[0], d);
            dist[0] = dk; bv = dk;
        }
#pragma unroll
        for (int k = 1; k < KPT; ++k) {
            float dx = x[k] - cx, dy = y[k] - cy, dz = z[k] - cz;
            float d  = ((dx * dx) + (dy * dy)) + (dz * dz);
            float dk = fminf(dist[k], d);
            dist[k] = dk;
            // ascending k + strict > keeps the smallest index on ties
            if (dk > bv) { bv = dk; bk = k; }
        }
        const int bi = (bk << 8) + t;   // global point index (idx = k*256 + t)
        unsigned long long key =
            ((unsigned long long)__float_as_uint(bv) << 32) | (unsigned)(~bi);

        // ---- wave argmax reduce on packed key ----
#pragma unroll
        for (int off = 32; off >= 1; off >>= 1) {
            unsigned long long o = __shfl_down(key, off);
            if (o > key) key = o;
        }
        const int par = it & 1;
        if (lane == 0) pk[par][w] = key;
        __syncthreads();

        // ---- all threads fold the 4 wave partials (broadcast LDS reads) ----
        unsigned long long k0 = pk[par][0], k1 = pk[par][1];
        unsigned long long k2 = pk[par][2], k3 = pk[par][3];
        if (k1 > k0) k0 = k1;
        if (k3 > k2) k2 = k3;
        if (k2 > k0) k0 = k2;
        const int idx = ~(int)(unsigned)k0;          // recover winning index
        cx = px[idx]; cy = py[idx]; cz = pz[idx];    // broadcast LDS reads
        if (t == 0) {
            float* o = new_xyz + ((size_t)b * NPOINT + it) * 3;
            o[0] = cx; o[1] = cy; o[2] = cz;
        }
    }
}

// ---------------------------------------------------------------------------
// Ball query: one wave per center. Ascending scan collects the first (i.e.
// smallest-index) NSAMPLE points with d2 < r2, padded with the first hit.
// ---------------------------------------------------------------------------
__global__ __launch_bounds__(256) void ballq_kernel(
    const float* __restrict__ points, const float* __restrict__ new_xyz,
    int* __restrict__ ballidx)
{
#pragma clang fp contract(off)
    const int wid  = (int)((blockIdx.x * 256 + threadIdx.x) >> 6);
    const int lane = threadIdx.x & 63;
    const int b = wid / NPOINT;
    const float* ctr = new_xyz + (size_t)wid * 3;
    const float cx = ctr[0], cy = ctr[1], cz = ctr[2];
    const float* pts = points + (size_t)b * NPTS * 3;
    int* out = ballidx + (size_t)wid * NSAMPLE;
    // NumPy/JAX promote the python double 0.04 to f32 — NOT 0.2f*0.2f.
    const float r2 = (float)(0.2 * 0.2);

    int cnt = 0;
    int first = 0;
    bool havefirst = false;
    for (int base = 0; base < NPTS && cnt < NSAMPLE; base += 64) {
        const int j = base + lane;
        float dx = pts[3 * j + 0] - cx;
        float dy = pts[3 * j + 1] - cy;
        float dz = pts[3 * j + 2] - cz;
        float d2 = ((dx * dx) + (dy * dy)) + (dz * dz);
        const bool in = d2 < r2;
        unsigned long long m = __ballot(in);
        if (in) {
            int pos = cnt + __popcll(m & ((1ull << lane) - 1ull));
            if (pos < NSAMPLE) out[pos] = j;
        }
        if (!havefirst && m != 0ull) {
            first = base + (__ffsll((long long)m) - 1);
            havefirst = true;
        }
        cnt += __popcll(m);
    }
    if (lane >= cnt && lane < NSAMPLE) out[lane] = first;  // pad with first
}

// ---------------------------------------------------------------------------
// Gather + conv: block = NP centers, 128 threads = 128 output channels.
// g[p][c][s] staged in LDS; fp32 FMA accumulate (tolerance is loose here).
// ---------------------------------------------------------------------------
__global__ __launch_bounds__(128) void conv_kernel(
    const float* __restrict__ points, const float* __restrict__ features,
    const float* __restrict__ weight, const float* __restrict__ new_xyz,
    const int* __restrict__ ballidx, float* __restrict__ conv_out)
{
    __shared__ float g[NP][NCH][NSAMPLE];
    const int t = threadIdx.x;
    const int bp0 = blockIdx.x * NP;                // global center index base
    const int b = bp0 / NPOINT;
    const float* pts = points + (size_t)b * NPTS * 3;
    const float* fts = features + (size_t)b * NPTS * 64;

    // gather: 128 slots == 128 threads; slot = p*32+s
    {
        const int p = t >> 5;
        const int s = t & 31;
        const int ci = bp0 + p;
        const int j = ballidx[(size_t)ci * NSAMPLE + s];
        const float* ctr = new_xyz + (size_t)ci * 3;
        const float* pj = pts + 3 * j;
        g[p][0][s] = pj[0] - ctr[0];
        g[p][1][s] = pj[1] - ctr[1];
        g[p][2][s] = pj[2] - ctr[2];
        const float4* fj = (const float4*)(fts + (size_t)j * 64);
#pragma unroll
        for (int c4 = 0; c4 < 16; ++c4) {
            float4 v = fj[c4];
            g[p][3 + 4 * c4 + 0][s] = v.x;
            g[p][3 + 4 * c4 + 1][s] = v.y;
            g[p][3 + 4 * c4 + 2][s] = v.z;
            g[p][3 + 4 * c4 + 3][s] = v.w;
        }
    }
    __syncthreads();

    const int o = t;
    float acc0 = 0.f, acc1 = 0.f, acc2 = 0.f, acc3 = 0.f;
    const float* wr = weight + (size_t)o * NCH * NSAMPLE;
    for (int c = 0; c < NCH; ++c) {
        const float4* w4 = (const float4*)(wr + c * NSAMPLE);
#pragma unroll
        for (int s4 = 0; s4 < 8; ++s4) {
            float4 wv = w4[s4];
            float4 g0 = *(const float4*)&g[0][c][s4 * 4];
            float4 g1 = *(const float4*)&g[1][c][s4 * 4];
            float4 g2 = *(const float4*)&g[2][c][s4 * 4];
            float4 g3 = *(const float4*)&g[3][c][s4 * 4];
            acc0 += g0.x * wv.x + g0.y * wv.y + g0.z * wv.z + g0.w * wv.w;
            acc1 += g1.x * wv.x + g1.y * wv.y + g1.z * wv.z + g1.w * wv.w;
            acc2 += g2.x * wv.x + g2.y * wv.y + g2.z * wv.z + g2.w * wv.w;
            acc3 += g3.x * wv.x + g3.y * wv.y + g3.z * wv.z + g3.w * wv.w;
        }
    }
    float* outp = conv_out + (size_t)bp0 * NOUT;
    outp[0 * NOUT + o] = acc0;
    outp[1 * NOUT + o] = acc1;
    outp[2 * NOUT + o] = acc2;
    outp[3 * NOUT + o] = acc3;
}

extern "C" void kernel_launch(void* const* d_in, const int* in_sizes, int n_in,
                              void* d_out, int out_size, void* d_ws, size_t ws_size,
                              hipStream_t stream)
{
    const float* points   = (const float*)d_in[0];
    const float* features = (const float*)d_in[1];
    const float* weight   = (const float*)d_in[2];

    float* new_xyz = (float*)d_out;                              // (4,2048,3)
    float* conv    = (float*)d_out + (size_t)BATCH * NPOINT * 3; // (4,2048,128)

    int* ballidx = (int*)d_ws;                 // (4,2048,32)

    fps_kernel<<<BATCH, FPS_T, 0, stream>>>(points, new_xyz);
    ballq_kernel<<<(BATCH * NPOINT * 64) / 256, 256, 0, stream>>>(points, new_xyz, ballidx);
    conv_kernel<<<(BATCH * NPOINT) / NP, 128, 0, stream>>>(points, features, weight, new_xyz, ballidx, conv);
}

// Round 4
// 2220.047 us; speedup vs baseline: 2.8341x; 1.1447x over previous
//
#include <hip/hip_runtime.h>

#define BATCH   4
#define NPTS    8192
#define NPOINT  2048
#define NSAMPLE 32
#define NCH     67
#define NOUT    128
#define NP      4      // centers per conv block
#define FPS_T   256
#define KPT     (NPTS / FPS_T)   // 32 points per thread
#define NWAVE   (FPS_T / 64)     // 4 waves

// DPP ctrl encodings (gfx9/CDNA)
#define DPP_ROW_SHR1   0x111
#define DPP_ROW_SHR2   0x112
#define DPP_ROW_SHR4   0x114
#define DPP_ROW_SHR8   0x118
#define DPP_ROW_BCAST15 0x142
#define DPP_ROW_BCAST31 0x143

// max-combine one DPP hop on a packed u64 key (halves move coherently since
// both use the same ctrl; bound_ctrl=1 zero-fills edges, and 0 is the max
// identity here because every real key has ~idx low bits != 0).
#define DPP_MAX_HOP(key, ctrl)                                                 \
    {                                                                          \
        int _lo = (int)(unsigned)(key);                                        \
        int _hi = (int)(unsigned)((key) >> 32);                                \
        int _olo = __builtin_amdgcn_update_dpp(0, _lo, (ctrl), 0xF, 0xF, true);\
        int _ohi = __builtin_amdgcn_update_dpp(0, _hi, (ctrl), 0xF, 0xF, true);\
        unsigned long long _o =                                                \
            ((unsigned long long)(unsigned)_ohi << 32) | (unsigned)_olo;       \
        if (_o > (key)) (key) = _o;                                            \
    }

// ---------------------------------------------------------------------------
// FPS: one block per batch, 256 threads (1 wave/SIMD pinned), 32 pts/thread
// in arch VGPRs. Bit-exact vs reference: contract off, sum order
// ((dx^2+dy^2)+dz^2), argmax = first occurrence (smallest index on ties).
// Key = (dist_bits<<32)|~idx. Wave reduce = 6 DPP max hops (lane 63 wins);
// one barrier/iter (parity-double-buffered wave slots); all threads fold the
// 4 wave keys and broadcast-read the winning coords from the LDS point cache.
// ---------------------------------------------------------------------------
__global__ __launch_bounds__(FPS_T, 1)
__attribute__((amdgpu_waves_per_eu(1, 1)))
void fps_kernel(const float* __restrict__ points, float* __restrict__ new_xyz)
{
#pragma clang fp contract(off)
    const int b = blockIdx.x;
    const int t = threadIdx.x;
    const float* pts = points + (size_t)b * NPTS * 3;

    __shared__ float px[NPTS], py[NPTS], pz[NPTS];
    __shared__ unsigned long long pk[2][NWAVE];

    float x[KPT], y[KPT], z[KPT], dist[KPT];
#pragma unroll
    for (int k = 0; k < KPT; ++k) {
        const int i = (k << 8) + t;
        const float xx = pts[3 * i + 0];
        const float yy = pts[3 * i + 1];
        const float zz = pts[3 * i + 2];
        x[k] = xx; y[k] = yy; z[k] = zz;
        dist[k] = 10000000000.0f;
        px[i] = xx; py[i] = yy; pz[i] = zz;
    }

    float cx = pts[0], cy = pts[1], cz = pts[2];  // first center = point 0
    if (t == 0) {
        float* o = new_xyz + (size_t)b * NPOINT * 3;
        o[0] = cx; o[1] = cy; o[2] = cz;
    }
    const int lane = t & 63;
    const int w    = t >> 6;
    __syncthreads();

    for (int it = 1; it < NPOINT; ++it) {
        // ---- phase A: min-update + thread-local argmax (k index only) ----
        float bv; int bk = 0;
        {
            float dx = x[0] - cx, dy = y[0] - cy, dz = z[0] - cz;
            float d  = ((dx * dx) + (dy * dy)) + (dz * dz);
            float dk = fminf(dist[0], d);
            dist[0] = dk; bv = dk;
        }
#pragma unroll
        for (int k = 1; k < KPT; ++k) {
            float dx = x[k] - cx, dy = y[k] - cy, dz = z[k] - cz;
            float d  = ((dx * dx) + (dy * dy)) + (dz * dz);
            float dk = fminf(dist[k], d);
            dist[k] = dk;
            // ascending k + strict > keeps the smallest index on ties
            if (dk > bv) { bv = dk; bk = k; }
        }
        const int bi = (bk << 8) + t;   // global point index (idx = k*256 + t)
        unsigned long long key =
            ((unsigned long long)__float_as_uint(bv) << 32) | (unsigned)(~bi);

        // ---- wave argmax reduce: 6 DPP max hops, lane 63 ends with max ----
        DPP_MAX_HOP(key, DPP_ROW_SHR1);
        DPP_MAX_HOP(key, DPP_ROW_SHR2);
        DPP_MAX_HOP(key, DPP_ROW_SHR4);
        DPP_MAX_HOP(key, DPP_ROW_SHR8);
        DPP_MAX_HOP(key, DPP_ROW_BCAST15);
        DPP_MAX_HOP(key, DPP_ROW_BCAST31);

        const int par = it & 1;
        if (lane == 63) pk[par][w] = key;
        __syncthreads();

        // ---- all threads fold the 4 wave partials (broadcast LDS reads) ----
        unsigned long long k0 = pk[par][0], k1 = pk[par][1];
        unsigned long long k2 = pk[par][2], k3 = pk[par][3];
        if (k1 > k0) k0 = k1;
        if (k3 > k2) k2 = k3;
        if (k2 > k0) k0 = k2;
        const int idx = ~(int)(unsigned)k0;          // recover winning index
        cx = px[idx]; cy = py[idx]; cz = pz[idx];    // broadcast LDS reads
        if (t == 0) {
            float* o = new_xyz + ((size_t)b * NPOINT + it) * 3;
            o[0] = cx; o[1] = cy; o[2] = cz;
        }
    }
}

// ---------------------------------------------------------------------------
// Ball query: one wave per center. Ascending scan collects the first (i.e.
// smallest-index) NSAMPLE points with d2 < r2, padded with the first hit.
// ---------------------------------------------------------------------------
__global__ __launch_bounds__(256) void ballq_kernel(
    const float* __restrict__ points, const float* __restrict__ new_xyz,
    int* __restrict__ ballidx)
{
#pragma clang fp contract(off)
    const int wid  = (int)((blockIdx.x * 256 + threadIdx.x) >> 6);
    const int lane = threadIdx.x & 63;
    const int b = wid / NPOINT;
    const float* ctr = new_xyz + (size_t)wid * 3;
    const float cx = ctr[0], cy = ctr[1], cz = ctr[2];
    const float* pts = points + (size_t)b * NPTS * 3;
    int* out = ballidx + (size_t)wid * NSAMPLE;
    // NumPy/JAX promote the python double 0.04 to f32 — NOT 0.2f*0.2f.
    const float r2 = (float)(0.2 * 0.2);

    int cnt = 0;
    int first = 0;
    bool havefirst = false;
    for (int base = 0; base < NPTS && cnt < NSAMPLE; base += 64) {
        const int j = base + lane;
        float dx = pts[3 * j + 0] - cx;
        float dy = pts[3 * j + 1] - cy;
        float dz = pts[3 * j + 2] - cz;
        float d2 = ((dx * dx) + (dy * dy)) + (dz * dz);
        const bool in = d2 < r2;
        unsigned long long m = __ballot(in);
        if (in) {
            int pos = cnt + __popcll(m & ((1ull << lane) - 1ull));
            if (pos < NSAMPLE) out[pos] = j;
        }
        if (!havefirst && m != 0ull) {
            first = base + (__ffsll((long long)m) - 1);
            havefirst = true;
        }
        cnt += __popcll(m);
    }
    if (lane >= cnt && lane < NSAMPLE) out[lane] = first;  // pad with first
}

// ---------------------------------------------------------------------------
// Gather + conv: block = NP centers, 128 threads = 128 output channels.
// g[p][c][s] staged in LDS; fp32 FMA accumulate (tolerance is loose here).
// ---------------------------------------------------------------------------
__global__ __launch_bounds__(128) void conv_kernel(
    const float* __restrict__ points, const float* __restrict__ features,
    const float* __restrict__ weight, const float* __restrict__ new_xyz,
    const int* __restrict__ ballidx, float* __restrict__ conv_out)
{
    __shared__ float g[NP][NCH][NSAMPLE];
    const int t = threadIdx.x;
    const int bp0 = blockIdx.x * NP;                // global center index base
    const int b = bp0 / NPOINT;
    const float* pts = points + (size_t)b * NPTS * 3;
    const float* fts = features + (size_t)b * NPTS * 64;

    // gather: 128 slots == 128 threads; slot = p*32+s
    {
        const int p = t >> 5;
        const int s = t & 31;
        const int ci = bp0 + p;
        const int j = ballidx[(size_t)ci * NSAMPLE + s];
        const float* ctr = new_xyz + (size_t)ci * 3;
        const float* pj = pts + 3 * j;
        g[p][0][s] = pj[0] - ctr[0];
        g[p][1][s] = pj[1] - ctr[1];
        g[p][2][s] = pj[2] - ctr[2];
        const float4* fj = (const float4*)(fts + (size_t)j * 64);
#pragma unroll
        for (int c4 = 0; c4 < 16; ++c4) {
            float4 v = fj[c4];
            g[p][3 + 4 * c4 + 0][s] = v.x;
            g[p][3 + 4 * c4 + 1][s] = v.y;
            g[p][3 + 4 * c4 + 2][s] = v.z;
            g[p][3 + 4 * c4 + 3][s] = v.w;
        }
    }
    __syncthreads();

    const int o = t;
    float acc0 = 0.f, acc1 = 0.f, acc2 = 0.f, acc3 = 0.f;
    const float* wr = weight + (size_t)o * NCH * NSAMPLE;
    for (int c = 0; c < NCH; ++c) {
        const float4* w4 = (const float4*)(wr + c * NSAMPLE);
#pragma unroll
        for (int s4 = 0; s4 < 8; ++s4) {
            float4 wv = w4[s4];
            float4 g0 = *(const float4*)&g[0][c][s4 * 4];
            float4 g1 = *(const float4*)&g[1][c][s4 * 4];
            float4 g2 = *(const float4*)&g[2][c][s4 * 4];
            float4 g3 = *(const float4*)&g[3][c][s4 * 4];
            acc0 += g0.x * wv.x + g0.y * wv.y + g0.z * wv.z + g0.w * wv.w;
            acc1 += g1.x * wv.x + g1.y * wv.y + g1.z * wv.z + g1.w * wv.w;
            acc2 += g2.x * wv.x + g2.y * wv.y + g2.z * wv.z + g2.w * wv.w;
            acc3 += g3.x * wv.x + g3.y * wv.y + g3.z * wv.z + g3.w * wv.w;
        }
    }
    float* outp = conv_out + (size_t)bp0 * NOUT;
    outp[0 * NOUT + o] = acc0;
    outp[1 * NOUT + o] = acc1;
    outp[2 * NOUT + o] = acc2;
    outp[3 * NOUT + o] = acc3;
}

extern "C" void kernel_launch(void* const* d_in, const int* in_sizes, int n_in,
                              void* d_out, int out_size, void* d_ws, size_t ws_size,
                              hipStream_t stream)
{
    const float* points   = (const float*)d_in[0];
    const float* features = (const float*)d_in[1];
    const float* weight   = (const float*)d_in[2];

    float* new_xyz = (float*)d_out;                              // (4,2048,3)
    float* conv    = (float*)d_out + (size_t)BATCH * NPOINT * 3; // (4,2048,128)

    int* ballidx = (int*)d_ws;                 // (4,2048,32)

    fps_kernel<<<BATCH, FPS_T, 0, stream>>>(points, new_xyz);
    ballq_kernel<<<(BATCH * NPOINT * 64) / 256, 256, 0, stream>>>(points, new_xyz, ballidx);
    conv_kernel<<<(BATCH * NPOINT) / NP, 128, 0, stream>>>(points, features, weight, new_xyz, ballidx, conv);
}